// Round 1
// baseline (426.377 us; speedup 1.0000x reference)
//
#include <hip/hip_runtime.h>

// SSIM-like loss, restructured:
//   After one broadcast-conv all channels are identical: used slice for batch n is
//   3^n * G^(n+1)(channel_sum), G = 3x3 gaussian, zero padding clipped every pass.
//   Per sample: 5 moments of (A,B) -> closed-form term; sum 8 terms.

#define TR 64            // tile rows per block
#define TC 32            // tile cols per block (contiguous dim)
#define MAXH 8
#define BSTR 49          // float2 column stride (padded)
#define BROWS 83         // rows incl. OOB-read margin (max row index SR+2 = 82)

#define KA 0.03797616f
#define KB 0.044863533f
#define KC 0.053f

__global__ __launch_bounds__(256) void ssim_zero(double* acc) {
  int i = threadIdx.x;
  if (i < 48) acc[i] = 0.0;
}

__global__ __launch_bounds__(256) void ssim_main(const float* __restrict__ xp,
                                                 const float* __restrict__ yp,
                                                 double* __restrict__ acc) {
  __shared__ float2 bufA[BROWS * BSTR];   // 32.5 KB
  __shared__ float2 bufB[BROWS * BSTR];   // 32.5 KB  (total 65,072 B <= 64 KiB)

  const int bid = blockIdx.x;
  const int n = bid & 7;            // sample, interleaved for load balance
  const int tile = bid >> 3;        // 0..511
  const int tc = tile & 31;         // 32 col-tiles of 32
  const int tr = tile >> 5;         // 16 row-tiles of 64
  const int oy = tr * TR;
  const int ox = tc * TC;
  const int h = n + 1;              // conv passes needed
  const int SR = TR + 2 * h;
  const int SC = TC + 2 * h;

  const int tid = threadIdx.x;
  const int tx = tid & 15;
  const int ty = tid >> 4;

  const size_t base = (size_t)n * 3u * 1048576u;

  // ---- load channel-summed (x,y) tile with halo h; zeros outside image ----
  for (int i = ty; i < SR; i += 16) {
    const int gy = oy + i - h;
    const bool rin = (unsigned)gy < 1024u;
    for (int j = tx; j < SC; j += 16) {
      const int gx = ox + j - h;
      float2 v = make_float2(0.f, 0.f);
      if (rin && (unsigned)gx < 1024u) {
        const size_t off = base + (size_t)gy * 1024u + (unsigned)gx;
        v.x = xp[off] + xp[off + 1048576] + xp[off + 2097152];
        v.y = yp[off] + yp[off + 1048576] + yp[off + 2097152];
      }
      bufA[i * BSTR + j] = v;
    }
  }
  __syncthreads();

  // ---- h conv passes, ping-pong in LDS; valid region shrinks by 1/pass ----
  float2* cur = bufA;
  float2* nxt = bufB;
  for (int p = 1; p <= h; ++p) {
    const int rhi = SR - p;
    const int chi = SC - p;
    for (int i0 = p + 4 * ty; i0 < rhi; i0 += 64) {
      for (int j = p + tx; j < chi; j += 16) {
        float2 w[6][3];               // rows i0-1..i0+4, cols j-1..j+1
#pragma unroll
        for (int r = 0; r < 6; ++r)
#pragma unroll
          for (int q = 0; q < 3; ++q)
            w[r][q] = cur[(i0 - 1 + r) * BSTR + (j - 1 + q)];
        const int gx = ox + j - h;
        const bool cin = (unsigned)gx < 1024u;
#pragma unroll
        for (int r = 0; r < 4; ++r) {
          const int i = i0 + r;
          if (i >= rhi) break;
          const int gy = oy + i - h;
          float2 v = make_float2(0.f, 0.f);
          if (cin && ((unsigned)gy < 1024u)) {   // zero-pad semantics every pass
            v.x = KA * (w[r][0].x + w[r][2].x + w[r+2][0].x + w[r+2][2].x)
                + KB * (w[r][1].x + w[r+1][0].x + w[r+1][2].x + w[r+2][1].x)
                + KC * w[r+1][1].x;
            v.y = KA * (w[r][0].y + w[r][2].y + w[r+2][0].y + w[r+2][2].y)
                + KB * (w[r][1].y + w[r+1][0].y + w[r+1][2].y + w[r+2][1].y)
                + KC * w[r+1][1].y;
          }
          nxt[i * BSTR + j] = v;
        }
      }
    }
    __syncthreads();
    float2* t = cur; cur = nxt; nxt = t;
  }

  // ---- moments over central TRxTC region (scaled by 3^n), fp64 accum ----
  float scale = 1.f;
  for (int q = 0; q < n; ++q) scale *= 3.f;
  double sA = 0, sB = 0, sAA = 0, sBB = 0, sAB = 0;
#pragma unroll
  for (int r = 0; r < 4; ++r) {
    const int i = h + 4 * ty + r;
#pragma unroll
    for (int jj = 0; jj < 2; ++jj) {
      const int j = h + tx + 16 * jj;
      const float2 v = cur[i * BSTR + j];
      const float A = scale * v.x;
      const float B = scale * v.y;
      sA += (double)A; sB += (double)B;
      sAA += (double)A * (double)A;
      sBB += (double)B * (double)B;
      sAB += (double)A * (double)B;
    }
  }
  __syncthreads();               // done reading cur; reuse bufA for reduction
  double* red = (double*)bufA;   // 1280 doubles = 10 KB
  red[tid] = sA;
  red[256 + tid] = sB;
  red[512 + tid] = sAA;
  red[768 + tid] = sBB;
  red[1024 + tid] = sAB;
  __syncthreads();
  for (int s = 128; s > 0; s >>= 1) {
    if (tid < s) {
#pragma unroll
      for (int k = 0; k < 5; ++k) red[k * 256 + tid] += red[k * 256 + tid + s];
    }
    __syncthreads();
  }
  if (tid == 0) {
#pragma unroll
    for (int k = 0; k < 5; ++k) atomicAdd(&acc[n * 5 + k], red[k * 256]);
  }
}

__global__ void ssim_final(const double* __restrict__ acc, float* __restrict__ out) {
  if (threadIdx.x == 0 && blockIdx.x == 0) {
    const double C1 = 6.5025;     // (0.01*255)^2
    const double C2 = 58.5225;    // (0.03*255)^2
    const double N = 1048576.0;
    double tot = 0.0;
    for (int n = 0; n < 8; ++n) {
      const double S1 = acc[n*5+0], S2 = acc[n*5+1], S3 = acc[n*5+2],
                   S4 = acc[n*5+3], S5 = acc[n*5+4];
      const double mA = S1 / N, mB = S2 / N;
      const double varA = (S3 - N * mA * mA) / (N - 1.0);
      const double varB = (S4 - N * mB * mB) / (N - 1.0);
      const double cov  = (S5 - N * mA * mB) / (N - 1.0);
      const double term = ((2.0 * mA * mB + C1) * (2.0 * cov + C2)) /
                          ((mA * mA + mB * mB + C1) *
                           (varA * varA + varB * varB + C2));
      tot += term;
    }
    out[0] = (float)tot;
  }
}

extern "C" void kernel_launch(void* const* d_in, const int* in_sizes, int n_in,
                              void* d_out, int out_size, void* d_ws, size_t ws_size,
                              hipStream_t stream) {
  const float* x = (const float*)d_in[0];
  const float* y = (const float*)d_in[1];
  double* acc = (double*)d_ws;           // 40 doubles used
  float* out = (float*)d_out;

  ssim_zero<<<1, 256, 0, stream>>>(acc);
  ssim_main<<<4096, 256, 0, stream>>>(x, y, acc);
  ssim_final<<<1, 64, 0, stream>>>(acc, out);
}

// Round 2
// 325.170 us; speedup vs baseline: 1.3112x; 1.3112x over previous
//
#include <hip/hip_runtime.h>

// SSIM-like loss, fully factored:
//   Used slice for batch n is 3^n * P^(n+1)(channel_sum), P = Z*V*H (3x3 separable
//   gaussian with zero-pad, clipped to image every pass).
//   Zr commutes with H, Zc with V  =>  P = (Zr V)(Zc H), and the two factors
//   commute  =>  P^h = (Zr V)^h (Zc H)^h : ONE vertical (2h+1)-tap conv and ONE
//   horizontal (2h+1)-tap conv, with exact edge-modified weight rows for outputs
//   within h of the border (tiny in-kernel recurrence table).
//   Then 5 moments -> closed-form term per sample; sum 8 terms.

#define TRR 64           // tile rows
#define TCC 32           // tile cols
#define MAXH 8
#define BSTR 49          // buf float2 stride (SC <= 48, +1 pad)
#define BROW 80          // SR <= 80
#define TSTR 33          // tbuf float2 stride (32 + pad)

// 3x3 kernel is separable: K = v v^T, v = (PC, QC, PC); PC=sqrt(a), QC=b/PC
#define PC 0.19487473f
#define QC 0.23021731f

__global__ __launch_bounds__(256) void ssim_zero(double* acc) {
  int i = threadIdx.x;
  if (i < 48) acc[i] = 0.0;
}

__global__ __launch_bounds__(256) void ssim_main(const float* __restrict__ xp,
                                                 const float* __restrict__ yp,
                                                 double* __restrict__ acc) {
  __shared__ float2 buf[BROW * BSTR];                 // 31,360 B
  __shared__ float2 tb[BROW * TSTR];                  // 21,120 B
  __shared__ float Wt[(MAXH + 1) * (2 * MAXH + 1)];   //    612 B  (total 53.1 KB -> 3 blk/CU)

  const int bid = blockIdx.x;
  const int n = bid & 7;            // sample (interleaved for CU load balance)
  const int tile = bid >> 3;
  const int tc = tile & 31;
  const int tr = tile >> 5;
  const int oy = tr * TRR;
  const int ox = tc * TCC;
  const int h = n + 1;              // conv passes composed
  const int K = 2 * h;              // tap count - 1
  const int SR = TRR + K;
  const int SC = TCC + K;

  const int tid = threadIdx.x;

  // ---- load channel-summed (x,y) tile with halo h; zeros outside image ----
  {
    const int tx = tid & 15, ty = tid >> 4;
    const size_t base = (size_t)n * 3145728u;
    for (int i = ty; i < SR; i += 16) {
      const int gy = oy + i - h;
      const bool rin = (unsigned)gy < 1024u;
      for (int j = tx; j < SC; j += 16) {
        const int gx = ox + j - h;
        float2 v = make_float2(0.f, 0.f);
        if (rin && ((unsigned)gx < 1024u)) {
          const size_t off = base + (size_t)gy * 1024u + (unsigned)gx;
          v.x = xp[off] + xp[off + 1048576] + xp[off + 2097152];
          v.y = yp[off] + yp[off + 1048576] + yp[off + 2097152];
        }
        buf[i * BSTR + j] = v;
      }
    }
  }

  // ---- exact clipped 1-D weight table: Wt[d][k], k=0..2h, input offset k-h.
  //      d = distance to edge (0..h-1 edge rows), d = h = centered row.
  //      Row d of ((Zr V)^h): r <- e_d (k=h); h times r'(k)=QC*r(k)+PC*(r(k-1)+r(k+1)),
  //      with r(k)=0 enforced for k < h-d (the per-pass clip).
  if (tid <= h) {
    float* Wd = Wt + tid * (K + 1);
    for (int k = 0; k <= K; ++k) Wd[k] = (k == h) ? 1.f : 0.f;
    const int kmin = h - tid;
    for (int m = 0; m < h; ++m) {
      float prev = 0.f;
      for (int k = kmin; k <= K; ++k) {
        const float cur = Wd[k];
        const float nxt = (k < K) ? Wd[k + 1] : 0.f;
        Wd[k] = QC * cur + PC * (prev + nxt);
        prev = cur;
      }
    }
  }
  __syncthreads();

  // ---- H pass: t(i,jt) = sum_k W(sel(gx),k') * buf(i, jt+k), all SR rows ----
  {
    const int jt = tid & 31;
    const int i0 = tid >> 5;          // 0..7
    const int gx = ox + jt;
    int dd = h, rv = 0;
    if (gx < h) { dd = gx; }
    else if (gx > 1023 - h) { dd = 1023 - gx; rv = 1; }
    const int A0 = dd * (K + 1) + (rv ? K : 0);
    const int s = rv ? -1 : 1;
    float2 a[10];
#pragma unroll
    for (int r = 0; r < 10; ++r) a[r] = make_float2(0.f, 0.f);
    for (int k = 0; k <= K; ++k) {
      const float w = Wt[A0 + s * k];
      const float2* col = buf + jt + k;
#pragma unroll
      for (int r = 0; r < 10; ++r) {
        const int i = i0 + 8 * r;
        if (i < SR) {
          const float2 c = col[i * BSTR];
          a[r].x += w * c.x; a[r].y += w * c.y;
        }
      }
    }
#pragma unroll
    for (int r = 0; r < 10; ++r) {
      const int i = i0 + 8 * r;
      if (i < SR) tb[i * TSTR + jt] = a[r];
    }
  }
  __syncthreads();

  // ---- V pass + moments: out(i,j) = sum_k W(sel(gy),k') * t(i+k, j) ----
  float scale = 1.f;
  for (int u = 0; u < n; ++u) scale *= 3.f;
  double sA = 0, sB = 0, sAA = 0, sBB = 0, sAB = 0;
  {
    const int jt = tid & 31;
    const int i0 = tid >> 5;
    float2 o[8];
#pragma unroll
    for (int r = 0; r < 8; ++r) o[r] = make_float2(0.f, 0.f);
    const bool uni = (oy >= h) && (oy + 63 <= 1023 - h);   // no edge rows in tile
    if (uni) {
      const int A0 = h * (K + 1);
      for (int k = 0; k <= K; ++k) {
        const float w = Wt[A0 + k];
        const float2* rowp = tb + (i0 + k) * TSTR + jt;
#pragma unroll
        for (int r = 0; r < 8; ++r) {
          const float2 c = rowp[8 * r * TSTR];
          o[r].x += w * c.x; o[r].y += w * c.y;
        }
      }
    } else {
      int A0r[8], sr[8];
#pragma unroll
      for (int r = 0; r < 8; ++r) {
        const int gy = oy + i0 + 8 * r;
        int dd = h, rv = 0;
        if (gy < h) { dd = gy; }
        else if (gy > 1023 - h) { dd = 1023 - gy; rv = 1; }
        A0r[r] = dd * (K + 1) + (rv ? K : 0);
        sr[r] = rv ? -1 : 1;
      }
      for (int k = 0; k <= K; ++k) {
        const float2* rowp = tb + (i0 + k) * TSTR + jt;
#pragma unroll
        for (int r = 0; r < 8; ++r) {
          const float w = Wt[A0r[r] + sr[r] * k];
          const float2 c = rowp[8 * r * TSTR];
          o[r].x += w * c.x; o[r].y += w * c.y;
        }
      }
    }
#pragma unroll
    for (int r = 0; r < 8; ++r) {
      const float A = scale * o[r].x;
      const float B = scale * o[r].y;
      sA += (double)A; sB += (double)B;
      sAA += (double)A * (double)A;
      sBB += (double)B * (double)B;
      sAB += (double)A * (double)B;
    }
  }

  // ---- block reduction (reuse buf) + one fp64 atomic x5 per block ----
  __syncthreads();
  double* red = (double*)buf;     // 1280 doubles = 10 KB
  red[tid] = sA;
  red[256 + tid] = sB;
  red[512 + tid] = sAA;
  red[768 + tid] = sBB;
  red[1024 + tid] = sAB;
  __syncthreads();
  for (int s = 128; s > 0; s >>= 1) {
    if (tid < s) {
#pragma unroll
      for (int k = 0; k < 5; ++k) red[k * 256 + tid] += red[k * 256 + tid + s];
    }
    __syncthreads();
  }
  if (tid == 0) {
#pragma unroll
    for (int k = 0; k < 5; ++k) atomicAdd(&acc[n * 5 + k], red[k * 256]);
  }
}

__global__ void ssim_final(const double* __restrict__ acc, float* __restrict__ out) {
  if (threadIdx.x == 0 && blockIdx.x == 0) {
    const double C1 = 6.5025;     // (0.01*255)^2
    const double C2 = 58.5225;    // (0.03*255)^2
    const double N = 1048576.0;
    double tot = 0.0;
    for (int n = 0; n < 8; ++n) {
      const double S1 = acc[n*5+0], S2 = acc[n*5+1], S3 = acc[n*5+2],
                   S4 = acc[n*5+3], S5 = acc[n*5+4];
      const double mA = S1 / N, mB = S2 / N;
      const double varA = (S3 - N * mA * mA) / (N - 1.0);
      const double varB = (S4 - N * mB * mB) / (N - 1.0);
      const double cov  = (S5 - N * mA * mB) / (N - 1.0);
      const double term = ((2.0 * mA * mB + C1) * (2.0 * cov + C2)) /
                          ((mA * mA + mB * mB + C1) *
                           (varA * varA + varB * varB + C2));
      tot += term;
    }
    out[0] = (float)tot;
  }
}

extern "C" void kernel_launch(void* const* d_in, const int* in_sizes, int n_in,
                              void* d_out, int out_size, void* d_ws, size_t ws_size,
                              hipStream_t stream) {
  const float* x = (const float*)d_in[0];
  const float* y = (const float*)d_in[1];
  double* acc = (double*)d_ws;           // 40 doubles used
  float* out = (float*)d_out;

  ssim_zero<<<1, 256, 0, stream>>>(acc);
  ssim_main<<<4096, 256, 0, stream>>>(x, y, acc);
  ssim_final<<<1, 64, 0, stream>>>(acc, out);
}

// Round 3
// 302.926 us; speedup vs baseline: 1.4075x; 1.0734x over previous
//
#include <hip/hip_runtime.h>

// SSIM-like loss, factored form:
//   term_n uses 3^n * (ZrV)^(n+1) (ZcH)^(n+1) (channel_sum), i.e. ONE vertical and
//   ONE horizontal (2h+1)-tap conv with exact edge-clipped weight rows.
//   Fixed 80x48 halo window (+-8) for all h; body templated on H so all tap loops
//   unroll; per-thread blocking along the conv direction; packed float2 math.

typedef float v2 __attribute__((ext_vector_type(2)));
typedef float v4 __attribute__((ext_vector_type(4)));

#define BSTR 50     // buf float2 stride (even -> 16B-aligned b128 rows, stride%32 dwords = 4)
#define TSTR 33     // tb  float2 stride

#define PC 0.19487473f
#define QC 0.23021731f

struct SharedMem {
  v2 buf[80 * BSTR];   // 32,000 B   input window (reused for reduction)
  v2 tb[80 * TSTR];    // 21,120 B   H-pass output
  float Wt[9 * 17];    //    612 B   clipped weight rows  (total 53,732 B -> 3 blk/CU)
};

__global__ __launch_bounds__(256) void ssim_zero(double* acc) {
  int i = threadIdx.x;
  if (i < 48) acc[i] = 0.0;
}

template <int H>
__device__ __forceinline__ void body(SharedMem& sm, int oy, int ox, int tr, int tc,
                                     const float* __restrict__ xp,
                                     const float* __restrict__ yp,
                                     double* __restrict__ acc) {
  constexpr int T = 2 * H + 1;
  constexpr int n = H - 1;
  constexpr int R0 = 8 - H, R1 = 71 + H;            // used rows in window
  const int tid = threadIdx.x;

  // ---- exact clipped 1-D weight rows: Wt[d][k], offset k-H; d=dist to edge, d=H centered
  if (tid <= H) {
    float* Wd = sm.Wt + tid * T;
    for (int k = 0; k < T; ++k) Wd[k] = (k == H) ? 1.f : 0.f;
    const int kmin = H - tid;
    for (int m = 0; m < H; ++m) {
      float prev = 0.f;
      for (int k = kmin; k < T; ++k) {
        const float cur = Wd[k];
        const float nxt = (k < T - 1) ? Wd[k + 1] : 0.f;
        Wd[k] = QC * cur + PC * (prev + nxt);
        prev = cur;
      }
    }
  }

  // ---- load: fixed window row r <-> gy=oy+r-8, col cell w <-> gx=ox+w-8 ----
  {
    constexpr int CC0 = (8 - H) >> 2, CC1 = (39 + H) >> 2;   // used 4-cell chunks
    const size_t base = (size_t)n * 3145728u;
    for (int c = tid; c < 960; c += 256) {
      const int row = c / 12;
      const int c4 = c - row * 12;
      if (row < R0 || row > R1 || c4 < CC0 || c4 > CC1) continue;
      const int gy = oy + row - 8;
      const int gx0 = ox + c4 * 4 - 8;
      v4 sx = {0.f, 0.f, 0.f, 0.f}, sy = {0.f, 0.f, 0.f, 0.f};
      if (((unsigned)gy < 1024u) && ((unsigned)gx0 < 1024u)) {
        const size_t off = base + (size_t)gy * 1024u + (unsigned)gx0;
        const v4* px = (const v4*)(xp + off);
        const v4* py = (const v4*)(yp + off);
        sx = px[0] + px[262144] + px[524288];      // 3-channel sum
        sy = py[0] + py[262144] + py[524288];
      }
      v2* d = sm.buf + row * BSTR + c4 * 4;
      d[0] = (v2){sx.x, sy.x}; d[1] = (v2){sx.y, sy.y};
      d[2] = (v2){sx.z, sy.z}; d[3] = (v2){sx.w, sy.w};
    }
  }
  __syncthreads();

  // ---- H pass: 8 contiguous cols/thread from a 24-cell register window ----
  {
    const int g = tid >> 6;          // col-group 0..3 (wave-uniform)
    const int i0 = tid & 63;
    constexpr int I0 = (8 - H) >> 1, I1 = (15 + H) >> 1;   // b128 read range
    const bool colEdge = (tc == 0) | (tc == 31);
    float cw[T];
    int A0[8], sg[8];
    if (colEdge) {
#pragma unroll
      for (int j = 0; j < 8; ++j) {
        const int gx = ox + g * 8 + j;
        int dd = H, rv = 0;
        if (gx < H) dd = gx;
        else if (gx > 1023 - H) { dd = 1023 - gx; rv = 1; }
        A0[j] = dd * T + (rv ? 2 * H : 0);
        sg[j] = rv ? -1 : 1;
      }
    } else {
#pragma unroll
      for (int k = 0; k < T; ++k) cw[k] = sm.Wt[H * T + k];
    }
    for (int r = i0; r < 80; r += 64) {
      if (r < R0 || r > R1) continue;
      const v4* s4 = (const v4*)(sm.buf + r * BSTR + g * 8);
      v2 win[24];
#pragma unroll
      for (int i = I0; i <= I1; ++i) {
        const v4 t = s4[i];
        win[2 * i] = (v2){t.x, t.y};
        win[2 * i + 1] = (v2){t.z, t.w};
      }
      v2 o[8] = {};
      if (!colEdge) {
#pragma unroll
        for (int k = 0; k < T; ++k)
#pragma unroll
          for (int j = 0; j < 8; ++j)
            o[j] += cw[k] * win[j + k + 8 - H];
      } else {
#pragma unroll
        for (int j = 0; j < 8; ++j)
          for (int k = 0; k < T; ++k)
            o[j] += sm.Wt[A0[j] + sg[j] * k] * win[j + k + 8 - H];
      }
      v2* d = sm.tb + r * TSTR + g * 8;
#pragma unroll
      for (int j = 0; j < 8; ++j) d[j] = o[j];
    }
  }
  __syncthreads();

  // ---- V pass + moments: 8 contiguous rows/thread from a 24-row register window ----
  float scale = 1.f;
#pragma unroll
  for (int u = 0; u < n; ++u) scale *= 3.f;
  double sA = 0, sB = 0, sAA = 0, sBB = 0, sAB = 0;
  {
    const int jt = tid & 31;
    const int i0 = tid >> 5;          // 0..7
    constexpr int C0 = 8 - H, C1 = 15 + H;
    v2 vwin[24];
#pragma unroll
    for (int c = C0; c <= C1; ++c)
      vwin[c] = sm.tb[(8 * i0 + c) * TSTR + jt];
    v2 o[8] = {};
    const bool rowEdge = (tr == 0) | (tr == 15);
    if (!rowEdge) {
      float cw[T];
#pragma unroll
      for (int k = 0; k < T; ++k) cw[k] = sm.Wt[H * T + k];
#pragma unroll
      for (int k = 0; k < T; ++k)
#pragma unroll
        for (int rr = 0; rr < 8; ++rr)
          o[rr] += cw[k] * vwin[rr + k + 8 - H];
    } else {
#pragma unroll
      for (int rr = 0; rr < 8; ++rr) {
        const int gy = oy + 8 * i0 + rr;
        int dd = H, rv = 0;
        if (gy < H) dd = gy;
        else if (gy > 1023 - H) { dd = 1023 - gy; rv = 1; }
        const int A0 = dd * T + (rv ? 2 * H : 0);
        const int s = rv ? -1 : 1;
        for (int k = 0; k < T; ++k)
          o[rr] += sm.Wt[A0 + s * k] * vwin[rr + k + 8 - H];
      }
    }
#pragma unroll
    for (int rr = 0; rr < 8; ++rr) {
      const float A = scale * o[rr].x;
      const float B = scale * o[rr].y;
      sA += (double)A; sB += (double)B;
      sAA += (double)A * (double)A;
      sBB += (double)B * (double)B;
      sAB += (double)A * (double)B;
    }
  }

  // ---- block reduction (reuse buf) + 5 fp64 atomics/block ----
  __syncthreads();
  double* red = (double*)sm.buf;   // 10 KB < 32 KB
  red[tid] = sA;
  red[256 + tid] = sB;
  red[512 + tid] = sAA;
  red[768 + tid] = sBB;
  red[1024 + tid] = sAB;
  __syncthreads();
  for (int s = 128; s > 0; s >>= 1) {
    if (tid < s) {
#pragma unroll
      for (int k = 0; k < 5; ++k) red[k * 256 + tid] += red[k * 256 + tid + s];
    }
    __syncthreads();
  }
  if (tid == 0) {
#pragma unroll
    for (int k = 0; k < 5; ++k) atomicAdd(&acc[n * 5 + k], red[k * 256]);
  }
}

__global__ __launch_bounds__(256) void ssim_main(const float* __restrict__ xp,
                                                 const float* __restrict__ yp,
                                                 double* __restrict__ acc) {
  __shared__ SharedMem sm;
  const int bid = blockIdx.x;
  const int n = bid & 7;            // sample (interleaved for CU load balance)
  const int tile = bid >> 3;
  const int tc = tile & 31;
  const int tr = tile >> 5;
  const int oy = tr * 64;
  const int ox = tc * 32;
  switch (n) {
    case 0: body<1>(sm, oy, ox, tr, tc, xp, yp, acc); break;
    case 1: body<2>(sm, oy, ox, tr, tc, xp, yp, acc); break;
    case 2: body<3>(sm, oy, ox, tr, tc, xp, yp, acc); break;
    case 3: body<4>(sm, oy, ox, tr, tc, xp, yp, acc); break;
    case 4: body<5>(sm, oy, ox, tr, tc, xp, yp, acc); break;
    case 5: body<6>(sm, oy, ox, tr, tc, xp, yp, acc); break;
    case 6: body<7>(sm, oy, ox, tr, tc, xp, yp, acc); break;
    default: body<8>(sm, oy, ox, tr, tc, xp, yp, acc); break;
  }
}

__global__ void ssim_final(const double* __restrict__ acc, float* __restrict__ out) {
  if (threadIdx.x == 0 && blockIdx.x == 0) {
    const double C1 = 6.5025;     // (0.01*255)^2
    const double C2 = 58.5225;    // (0.03*255)^2
    const double N = 1048576.0;
    double tot = 0.0;
    for (int n = 0; n < 8; ++n) {
      const double S1 = acc[n*5+0], S2 = acc[n*5+1], S3 = acc[n*5+2],
                   S4 = acc[n*5+3], S5 = acc[n*5+4];
      const double mA = S1 / N, mB = S2 / N;
      const double varA = (S3 - N * mA * mA) / (N - 1.0);
      const double varB = (S4 - N * mB * mB) / (N - 1.0);
      const double cov  = (S5 - N * mA * mB) / (N - 1.0);
      const double term = ((2.0 * mA * mB + C1) * (2.0 * cov + C2)) /
                          ((mA * mA + mB * mB + C1) *
                           (varA * varA + varB * varB + C2));
      tot += term;
    }
    out[0] = (float)tot;
  }
}

extern "C" void kernel_launch(void* const* d_in, const int* in_sizes, int n_in,
                              void* d_out, int out_size, void* d_ws, size_t ws_size,
                              hipStream_t stream) {
  const float* x = (const float*)d_in[0];
  const float* y = (const float*)d_in[1];
  double* acc = (double*)d_ws;           // 40 doubles used
  float* out = (float*)d_out;

  ssim_zero<<<1, 256, 0, stream>>>(acc);
  ssim_main<<<4096, 256, 0, stream>>>(x, y, acc);
  ssim_final<<<1, 64, 0, stream>>>(acc, out);
}

// Round 4
// 289.891 us; speedup vs baseline: 1.4708x; 1.0450x over previous
//
#include <hip/hip_runtime.h>

// SSIM-like loss, factored form:
//   term_n uses 3^n * (ZrV)^(n+1) (ZcH)^(n+1) (channel_sum): ONE vertical and ONE
//   horizontal (2h+1)-tap conv with exact edge-clipped weight rows (in-kernel
//   recurrence). Fixed 80x48 window; H-pass runs IN PLACE in buf (read->regs,
//   sync, write) so LDS = 32.6 KB -> 4 blocks/CU. fp32 moment partials
//   (var only enters as var^2 << C2, so fp32 partial error is invisible),
//   fp64 from block tree onward.

typedef float v2f __attribute__((ext_vector_type(2)));
typedef float v4f __attribute__((ext_vector_type(4)));

#define BSTR 50     // buf float2 stride (even -> 16B-aligned rows for b128)

#define PC 0.19487473f
#define QC 0.23021731f

struct SharedMem {
  v2f buf[80 * BSTR];   // 32,000 B  input window -> H output (in place) -> reduction
  float Wt[9 * 17];     //    612 B  clipped weight rows   (total 32,612 B -> 4 blk/CU)
};

__global__ __launch_bounds__(256) void ssim_zero(double* acc) {
  int i = threadIdx.x;
  if (i < 48) acc[i] = 0.0;
}

template <int H>
__device__ __forceinline__ void body(SharedMem& sm, int oy, int ox, int tr, int tc,
                                     const float* __restrict__ xp,
                                     const float* __restrict__ yp,
                                     double* __restrict__ acc) {
  constexpr int T = 2 * H + 1;
  constexpr int n = H - 1;
  constexpr int R0 = 8 - H, R1 = 71 + H;            // used window rows
  const int tid = threadIdx.x;

  // ---- exact clipped 1-D weight rows: Wt[d][k], input offset k-H;
  //      d = dist to edge (0..H-1), d = H = interior row.
  if (tid <= H) {
    float* Wd = sm.Wt + tid * T;
    for (int k = 0; k < T; ++k) Wd[k] = (k == H) ? 1.f : 0.f;
    const int kmin = H - tid;
    for (int m = 0; m < H; ++m) {
      float prev = 0.f;
      for (int k = kmin; k < T; ++k) {
        const float cur = Wd[k];
        const float nxt = (k < T - 1) ? Wd[k + 1] : 0.f;
        Wd[k] = QC * cur + PC * (prev + nxt);
        prev = cur;
      }
    }
  }

  // ---- load: window row r <-> gy=oy+r-8, col cell w <-> gx=ox+w-8; zeros outside ----
  {
    constexpr int CC0 = (8 - H) >> 2, CC1 = (39 + H) >> 2;   // used 4-cell chunks
    const size_t base = (size_t)n * 3145728u;
    for (int c = tid; c < 960; c += 256) {
      const int row = c / 12;
      const int c4 = c - row * 12;
      if (row < R0 || row > R1 || c4 < CC0 || c4 > CC1) continue;
      const int gy = oy + row - 8;
      const int gx0 = ox + c4 * 4 - 8;
      v4f sx = {0.f, 0.f, 0.f, 0.f}, sy = {0.f, 0.f, 0.f, 0.f};
      if (((unsigned)gy < 1024u) && ((unsigned)gx0 < 1024u)) {
        const size_t off = base + (size_t)gy * 1024u + (unsigned)gx0;
        const v4f* px = (const v4f*)(xp + off);
        const v4f* py = (const v4f*)(yp + off);
        sx = px[0] + px[262144] + px[524288];      // 3-channel sum
        sy = py[0] + py[262144] + py[524288];
      }
      v4f* d = (v4f*)(sm.buf + row * BSTR + c4 * 4);
      d[0] = (v4f){sx.x, sy.x, sx.y, sy.y};
      d[1] = (v4f){sx.z, sy.z, sx.w, sy.w};
    }
  }
  __syncthreads();

  // ---- H pass IN PLACE: all reads -> registers, sync, write back ----
  {
    const int g = tid >> 6;              // col-group 0..3 (wave-uniform)
    const int i0 = tid & 63;
    constexpr int I0 = (8 - H) >> 1, I1 = (15 + H) >> 1;   // b128 read range
    const bool colEdge = (tc == 0) | (tc == 31);
    float cw[T];
    int A0[8], sg[8];
    if (colEdge) {
#pragma unroll
      for (int j = 0; j < 8; ++j) {
        const int gx = ox + g * 8 + j;
        int dd = H, rv = 0;
        if (gx < H) dd = gx;
        else if (gx > 1023 - H) { dd = 1023 - gx; rv = 1; }
        A0[j] = dd * T + (rv ? 2 * H : 0);
        sg[j] = rv ? -1 : 1;
      }
    } else {
#pragma unroll
      for (int k = 0; k < T; ++k) cw[k] = sm.Wt[H * T + k];
    }

    auto htask = [&](v2f* o, int r) {
      const v4f* s4 = (const v4f*)(sm.buf + r * BSTR + g * 8);
      v2f win[24];
#pragma unroll
      for (int i = I0; i <= I1; ++i) {
        const v4f t = s4[i];
        win[2 * i] = (v2f){t.x, t.y};
        win[2 * i + 1] = (v2f){t.z, t.w};
      }
      if (!colEdge) {
#pragma unroll
        for (int k = 0; k < T; ++k)
#pragma unroll
          for (int j = 0; j < 8; ++j)
            o[j] += cw[k] * win[j + k + 8 - H];
      } else {
#pragma unroll
        for (int j = 0; j < 8; ++j)
          for (int k = 0; k < T; ++k)
            o[j] += sm.Wt[A0[j] + sg[j] * k] * win[j + k + 8 - H];
      }
    };

    v2f o1[8] = {}, o2[8] = {};
    const int r2 = i0 + 64;
    const bool val1 = (i0 >= R0);
    const bool val2 = (r2 <= R1);
    if (val1) htask(o1, i0);
    if (val2) htask(o2, r2);
    __syncthreads();                       // all reads done before any write
    if (val1) {
      v4f* d = (v4f*)(sm.buf + i0 * BSTR + g * 8 + 8);
#pragma unroll
      for (int jj = 0; jj < 4; ++jj)
        d[jj] = (v4f){o1[2 * jj].x, o1[2 * jj].y, o1[2 * jj + 1].x, o1[2 * jj + 1].y};
    }
    if (val2) {
      v4f* d = (v4f*)(sm.buf + r2 * BSTR + g * 8 + 8);
#pragma unroll
      for (int jj = 0; jj < 4; ++jj)
        d[jj] = (v4f){o2[2 * jj].x, o2[2 * jj].y, o2[2 * jj + 1].x, o2[2 * jj + 1].y};
    }
  }
  __syncthreads();

  // ---- V pass + fp32 moments: 8 contiguous rows/thread from register window ----
  constexpr float scales[8] = {1.f, 3.f, 9.f, 27.f, 81.f, 243.f, 729.f, 2187.f};
  const float scale = scales[n];
  float sA = 0.f, sB = 0.f, sAA = 0.f, sBB = 0.f, sAB = 0.f;
  {
    const int jt = tid & 31;
    const int iv = tid >> 5;             // 0..7
    constexpr int C0 = 8 - H, C1 = 15 + H;
    v2f vwin[24];
#pragma unroll
    for (int c = C0; c <= C1; ++c)
      vwin[c] = sm.buf[(8 * iv + c) * BSTR + 8 + jt];
    v2f o[8] = {};
    const bool rowEdge = (tr == 0) | (tr == 15);
    if (!rowEdge) {
      float cw2[T];
#pragma unroll
      for (int k = 0; k < T; ++k) cw2[k] = sm.Wt[H * T + k];
#pragma unroll
      for (int k = 0; k < T; ++k)
#pragma unroll
        for (int rr = 0; rr < 8; ++rr)
          o[rr] += cw2[k] * vwin[rr + k + 8 - H];
    } else {
#pragma unroll
      for (int rr = 0; rr < 8; ++rr) {
        const int gy = oy + 8 * iv + rr;
        int dd = H, rv = 0;
        if (gy < H) dd = gy;
        else if (gy > 1023 - H) { dd = 1023 - gy; rv = 1; }
        const int A0 = dd * T + (rv ? 2 * H : 0);
        const int s = rv ? -1 : 1;
        for (int k = 0; k < T; ++k)
          o[rr] += sm.Wt[A0 + s * k] * vwin[rr + k + 8 - H];
      }
    }
#pragma unroll
    for (int rr = 0; rr < 8; ++rr) {
      const float A = scale * o[rr].x;
      const float B = scale * o[rr].y;
      sA += A; sB += B;
      sAA += A * A; sBB += B * B; sAB += A * B;
    }
  }

  // ---- block reduction (reuse buf) + 5 fp64 atomics/block ----
  __syncthreads();                 // V reads complete before overwrite
  double* red = (double*)sm.buf;   // 10,240 B < 32,000 B
  red[tid] = (double)sA;
  red[256 + tid] = (double)sB;
  red[512 + tid] = (double)sAA;
  red[768 + tid] = (double)sBB;
  red[1024 + tid] = (double)sAB;
  __syncthreads();
  for (int s = 128; s > 0; s >>= 1) {
    if (tid < s) {
#pragma unroll
      for (int k = 0; k < 5; ++k) red[k * 256 + tid] += red[k * 256 + tid + s];
    }
    __syncthreads();
  }
  if (tid == 0) {
#pragma unroll
    for (int k = 0; k < 5; ++k) atomicAdd(&acc[n * 5 + k], red[k * 256]);
  }
}

__global__ __launch_bounds__(256, 4) void ssim_main(const float* __restrict__ xp,
                                                    const float* __restrict__ yp,
                                                    double* __restrict__ acc) {
  __shared__ SharedMem sm;
  const int bid = blockIdx.x;
  const int n = bid & 7;            // sample (interleaved for CU load balance)
  const int tile = bid >> 3;
  const int tc = tile & 31;
  const int tr = tile >> 5;
  const int oy = tr * 64;
  const int ox = tc * 32;
  switch (n) {
    case 0: body<1>(sm, oy, ox, tr, tc, xp, yp, acc); break;
    case 1: body<2>(sm, oy, ox, tr, tc, xp, yp, acc); break;
    case 2: body<3>(sm, oy, ox, tr, tc, xp, yp, acc); break;
    case 3: body<4>(sm, oy, ox, tr, tc, xp, yp, acc); break;
    case 4: body<5>(sm, oy, ox, tr, tc, xp, yp, acc); break;
    case 5: body<6>(sm, oy, ox, tr, tc, xp, yp, acc); break;
    case 6: body<7>(sm, oy, ox, tr, tc, xp, yp, acc); break;
    default: body<8>(sm, oy, ox, tr, tc, xp, yp, acc); break;
  }
}

__global__ void ssim_final(const double* __restrict__ acc, float* __restrict__ out) {
  if (threadIdx.x == 0 && blockIdx.x == 0) {
    const double C1 = 6.5025;     // (0.01*255)^2
    const double C2 = 58.5225;    // (0.03*255)^2
    const double N = 1048576.0;
    double tot = 0.0;
    for (int n = 0; n < 8; ++n) {
      const double S1 = acc[n*5+0], S2 = acc[n*5+1], S3 = acc[n*5+2],
                   S4 = acc[n*5+3], S5 = acc[n*5+4];
      const double mA = S1 / N, mB = S2 / N;
      const double varA = (S3 - N * mA * mA) / (N - 1.0);
      const double varB = (S4 - N * mB * mB) / (N - 1.0);
      const double cov  = (S5 - N * mA * mB) / (N - 1.0);
      const double term = ((2.0 * mA * mB + C1) * (2.0 * cov + C2)) /
                          ((mA * mA + mB * mB + C1) *
                           (varA * varA + varB * varB + C2));
      tot += term;
    }
    out[0] = (float)tot;
  }
}

extern "C" void kernel_launch(void* const* d_in, const int* in_sizes, int n_in,
                              void* d_out, int out_size, void* d_ws, size_t ws_size,
                              hipStream_t stream) {
  const float* x = (const float*)d_in[0];
  const float* y = (const float*)d_in[1];
  double* acc = (double*)d_ws;           // 40 doubles used
  float* out = (float*)d_out;

  ssim_zero<<<1, 256, 0, stream>>>(acc);
  ssim_main<<<4096, 256, 0, stream>>>(x, y, acc);
  ssim_final<<<1, 64, 0, stream>>>(acc, out);
}

// Round 5
// 247.637 us; speedup vs baseline: 1.7218x; 1.1706x over previous
//
#include <hip/hip_runtime.h>

// SSIM-like loss, factored form:
//   term_n uses 3^n * (ZrV)^(n+1) (ZcH)^(n+1) (channel_sum): ONE vertical and ONE
//   horizontal (2h+1)-tap conv with exact edge-clipped weight rows (in-kernel
//   recurrence). Fixed 80x48 window; H-pass in place in buf. fp32 moment partials,
//   fp64 from wave reduction onward.
//   Accumulation: 64 slots per sample (atomic contention 512 -> 8 per address);
//   wave-shfl block reduction (2 barriers, no 8-level LDS tree).

typedef float v2f __attribute__((ext_vector_type(2)));
typedef float v4f __attribute__((ext_vector_type(4)));

#define BSTR 50     // buf float2 stride (even -> 16B-aligned rows for b128)

#define PC 0.19487473f
#define QC 0.23021731f

#define NSLOT 64    // accumulation slots per sample

struct SharedMem {
  v2f buf[80 * BSTR];   // 32,000 B  input window -> H output (in place)
  float Wt[9 * 17];     //    612 B  clipped weight rows
  double wred[4 * 5];   //    160 B  per-wave partials (total ~32.8 KB)
};

__global__ __launch_bounds__(256) void ssim_zero(double* acc) {
  for (int i = threadIdx.x; i < 8 * NSLOT * 5; i += 256) acc[i] = 0.0;
}

template <int H>
__device__ __forceinline__ void body(SharedMem& sm, int oy, int ox, int tr, int tc,
                                     const float* __restrict__ xp,
                                     const float* __restrict__ yp,
                                     double* __restrict__ accn) {
  constexpr int T = 2 * H + 1;
  constexpr int n = H - 1;
  constexpr int R0 = 8 - H, R1 = 71 + H;            // used window rows
  const int tid = threadIdx.x;

  // ---- exact clipped 1-D weight rows: Wt[d][k], input offset k-H;
  //      d = dist to edge (0..H-1), d = H = interior row.
  if (tid <= H) {
    float* Wd = sm.Wt + tid * T;
    for (int k = 0; k < T; ++k) Wd[k] = (k == H) ? 1.f : 0.f;
    const int kmin = H - tid;
    for (int m = 0; m < H; ++m) {
      float prev = 0.f;
      for (int k = kmin; k < T; ++k) {
        const float cur = Wd[k];
        const float nxt = (k < T - 1) ? Wd[k + 1] : 0.f;
        Wd[k] = QC * cur + PC * (prev + nxt);
        prev = cur;
      }
    }
  }

  // ---- load: window row r <-> gy=oy+r-8, col cell w <-> gx=ox+w-8; zeros outside ----
  {
    constexpr int CC0 = (8 - H) >> 2, CC1 = (39 + H) >> 2;   // used 4-cell chunks
    const size_t base = (size_t)n * 3145728u;
    for (int c = tid; c < 960; c += 256) {
      const int row = c / 12;
      const int c4 = c - row * 12;
      if (row < R0 || row > R1 || c4 < CC0 || c4 > CC1) continue;
      const int gy = oy + row - 8;
      const int gx0 = ox + c4 * 4 - 8;
      v4f sx = {0.f, 0.f, 0.f, 0.f}, sy = {0.f, 0.f, 0.f, 0.f};
      if (((unsigned)gy < 1024u) && ((unsigned)gx0 < 1024u)) {
        const size_t off = base + (size_t)gy * 1024u + (unsigned)gx0;
        const v4f* px = (const v4f*)(xp + off);
        const v4f* py = (const v4f*)(yp + off);
        sx = px[0] + px[262144] + px[524288];      // 3-channel sum
        sy = py[0] + py[262144] + py[524288];
      }
      v4f* d = (v4f*)(sm.buf + row * BSTR + c4 * 4);
      d[0] = (v4f){sx.x, sy.x, sx.y, sy.y};
      d[1] = (v4f){sx.z, sy.z, sx.w, sy.w};
    }
  }
  __syncthreads();

  // ---- H pass IN PLACE: all reads -> registers, sync, write back ----
  {
    const int g = tid >> 6;              // col-group 0..3 (wave-uniform)
    const int i0 = tid & 63;
    constexpr int I0 = (8 - H) >> 1, I1 = (15 + H) >> 1;   // b128 read range
    const bool colEdge = (tc == 0) | (tc == 31);
    float cw[T];
    int A0[8], sg[8];
    if (colEdge) {
#pragma unroll
      for (int j = 0; j < 8; ++j) {
        const int gx = ox + g * 8 + j;
        int dd = H, rv = 0;
        if (gx < H) dd = gx;
        else if (gx > 1023 - H) { dd = 1023 - gx; rv = 1; }
        A0[j] = dd * T + (rv ? 2 * H : 0);
        sg[j] = rv ? -1 : 1;
      }
    } else {
#pragma unroll
      for (int k = 0; k < T; ++k) cw[k] = sm.Wt[H * T + k];
    }

    auto htask = [&](v2f* o, int r) {
      const v4f* s4 = (const v4f*)(sm.buf + r * BSTR + g * 8);
      v2f win[24];
#pragma unroll
      for (int i = I0; i <= I1; ++i) {
        const v4f t = s4[i];
        win[2 * i] = (v2f){t.x, t.y};
        win[2 * i + 1] = (v2f){t.z, t.w};
      }
      if (!colEdge) {
#pragma unroll
        for (int k = 0; k < T; ++k)
#pragma unroll
          for (int j = 0; j < 8; ++j)
            o[j] += cw[k] * win[j + k + 8 - H];
      } else {
#pragma unroll
        for (int j = 0; j < 8; ++j)
          for (int k = 0; k < T; ++k)
            o[j] += sm.Wt[A0[j] + sg[j] * k] * win[j + k + 8 - H];
      }
    };

    v2f o1[8] = {}, o2[8] = {};
    const int r2 = i0 + 64;
    const bool val1 = (i0 >= R0);
    const bool val2 = (r2 <= R1);
    if (val1) htask(o1, i0);
    if (val2) htask(o2, r2);
    __syncthreads();                       // all reads done before any write
    if (val1) {
      v4f* d = (v4f*)(sm.buf + i0 * BSTR + g * 8 + 8);
#pragma unroll
      for (int jj = 0; jj < 4; ++jj)
        d[jj] = (v4f){o1[2 * jj].x, o1[2 * jj].y, o1[2 * jj + 1].x, o1[2 * jj + 1].y};
    }
    if (val2) {
      v4f* d = (v4f*)(sm.buf + r2 * BSTR + g * 8 + 8);
#pragma unroll
      for (int jj = 0; jj < 4; ++jj)
        d[jj] = (v4f){o2[2 * jj].x, o2[2 * jj].y, o2[2 * jj + 1].x, o2[2 * jj + 1].y};
    }
  }
  __syncthreads();

  // ---- V pass + fp32 moments: 8 contiguous rows/thread from register window ----
  constexpr float scales[8] = {1.f, 3.f, 9.f, 27.f, 81.f, 243.f, 729.f, 2187.f};
  const float scale = scales[n];
  float sA = 0.f, sB = 0.f, sAA = 0.f, sBB = 0.f, sAB = 0.f;
  {
    const int jt = tid & 31;
    const int iv = tid >> 5;             // 0..7
    constexpr int C0 = 8 - H, C1 = 15 + H;
    v2f vwin[24];
#pragma unroll
    for (int c = C0; c <= C1; ++c)
      vwin[c] = sm.buf[(8 * iv + c) * BSTR + 8 + jt];
    v2f o[8] = {};
    const bool rowEdge = (tr == 0) | (tr == 15);
    if (!rowEdge) {
      float cw2[T];
#pragma unroll
      for (int k = 0; k < T; ++k) cw2[k] = sm.Wt[H * T + k];
#pragma unroll
      for (int k = 0; k < T; ++k)
#pragma unroll
        for (int rr = 0; rr < 8; ++rr)
          o[rr] += cw2[k] * vwin[rr + k + 8 - H];
    } else {
#pragma unroll
      for (int rr = 0; rr < 8; ++rr) {
        const int gy = oy + 8 * iv + rr;
        int dd = H, rv = 0;
        if (gy < H) dd = gy;
        else if (gy > 1023 - H) { dd = 1023 - gy; rv = 1; }
        const int A0 = dd * T + (rv ? 2 * H : 0);
        const int s = rv ? -1 : 1;
        for (int k = 0; k < T; ++k)
          o[rr] += sm.Wt[A0 + s * k] * vwin[rr + k + 8 - H];
      }
    }
#pragma unroll
    for (int rr = 0; rr < 8; ++rr) {
      const float A = scale * o[rr].x;
      const float B = scale * o[rr].y;
      sA += A; sB += B;
      sAA += A * A; sBB += B * B; sAB += A * B;
    }
  }

  // ---- wave shfl reduction -> 4 wave partials -> 5 low-contention atomics ----
  double v[5] = {(double)sA, (double)sB, (double)sAA, (double)sBB, (double)sAB};
#pragma unroll
  for (int off = 32; off > 0; off >>= 1) {
#pragma unroll
    for (int k = 0; k < 5; ++k) v[k] += __shfl_down(v[k], off, 64);
  }
  const int lane = tid & 63, wv = tid >> 6;
  if (lane == 0) {
#pragma unroll
    for (int k = 0; k < 5; ++k) sm.wred[wv * 5 + k] = v[k];
  }
  __syncthreads();
  if (tid == 0) {
#pragma unroll
    for (int k = 0; k < 5; ++k)
      atomicAdd(&accn[k], sm.wred[k] + sm.wred[5 + k] + sm.wred[10 + k] + sm.wred[15 + k]);
  }
}

__global__ __launch_bounds__(256, 5) void ssim_main(const float* __restrict__ xp,
                                                    const float* __restrict__ yp,
                                                    double* __restrict__ acc) {
  __shared__ SharedMem sm;
  const int bid = blockIdx.x;
  const int n = bid & 7;            // sample (interleaved for CU load balance)
  const int tile = bid >> 3;
  const int tc = tile & 31;
  const int tr = tile >> 5;
  const int oy = tr * 64;
  const int ox = tc * 32;
  const int slot = tile & (NSLOT - 1);
  double* accn = acc + (n * NSLOT + slot) * 5;
  switch (n) {
    case 0: body<1>(sm, oy, ox, tr, tc, xp, yp, accn); break;
    case 1: body<2>(sm, oy, ox, tr, tc, xp, yp, accn); break;
    case 2: body<3>(sm, oy, ox, tr, tc, xp, yp, accn); break;
    case 3: body<4>(sm, oy, ox, tr, tc, xp, yp, accn); break;
    case 4: body<5>(sm, oy, ox, tr, tc, xp, yp, accn); break;
    case 5: body<6>(sm, oy, ox, tr, tc, xp, yp, accn); break;
    case 6: body<7>(sm, oy, ox, tr, tc, xp, yp, accn); break;
    default: body<8>(sm, oy, ox, tr, tc, xp, yp, accn); break;
  }
}

__global__ __launch_bounds__(256) void ssim_final(const double* __restrict__ acc,
                                                  float* __restrict__ out) {
  // 256 threads = 8 samples x 32 lanes; lane l sums slots l and l+32.
  __shared__ double terms[8];
  const int tid = threadIdx.x;
  const int s = tid >> 5;
  const int l = tid & 31;
  double v[5];
#pragma unroll
  for (int k = 0; k < 5; ++k)
    v[k] = acc[(s * NSLOT + l) * 5 + k] + acc[(s * NSLOT + l + 32) * 5 + k];
#pragma unroll
  for (int off = 16; off > 0; off >>= 1) {
#pragma unroll
    for (int k = 0; k < 5; ++k) v[k] += __shfl_down(v[k], off, 32);
  }
  if (l == 0) {
    const double C1 = 6.5025;     // (0.01*255)^2
    const double C2 = 58.5225;    // (0.03*255)^2
    const double N = 1048576.0;
    const double mA = v[0] / N, mB = v[1] / N;
    const double varA = (v[2] - N * mA * mA) / (N - 1.0);
    const double varB = (v[3] - N * mB * mB) / (N - 1.0);
    const double cov  = (v[4] - N * mA * mB) / (N - 1.0);
    terms[s] = ((2.0 * mA * mB + C1) * (2.0 * cov + C2)) /
               ((mA * mA + mB * mB + C1) * (varA * varA + varB * varB + C2));
  }
  __syncthreads();
  if (tid == 0) {
    double tot = 0.0;
    for (int i = 0; i < 8; ++i) tot += terms[i];
    out[0] = (float)tot;
  }
}

extern "C" void kernel_launch(void* const* d_in, const int* in_sizes, int n_in,
                              void* d_out, int out_size, void* d_ws, size_t ws_size,
                              hipStream_t stream) {
  const float* x = (const float*)d_in[0];
  const float* y = (const float*)d_in[1];
  double* acc = (double*)d_ws;           // 8*64*5 doubles = 20 KB
  float* out = (float*)d_out;

  ssim_zero<<<1, 256, 0, stream>>>(acc);
  ssim_main<<<4096, 256, 0, stream>>>(x, y, acc);
  ssim_final<<<1, 256, 0, stream>>>(acc, out);
}